// Round 1
// baseline (166.612 us; speedup 1.0000x reference)
//
#include <hip/hip_runtime.h>

#define NB 22
#define NFR_B 7499
#define BATCH 32
#define ROWLEN 960000
#define NFTOT (BATCH * NFR_B)

__constant__ int c_bands[NB] = {0,4,8,12,16,20,24,28,32,40,44,48,52,56,64,72,80,88,96,104,112,128};

__global__ __launch_bounds__(256, 4)
void feat_kernel(const float* __restrict__ x, float* __restrict__ out) {
    const int lane = threadIdx.x & 63;
    const int wid  = threadIdx.x >> 6;
    const int gwave  = blockIdx.x * (blockDim.x >> 6) + wid;
    const int nwaves = gridDim.x * (blockDim.x >> 6);

    __shared__ float lds[4][160];
    float* pwbuf = lds[wid];         // pw[0..135] (128..135 zero pad)
    float* lgbuf = lds[wid] + 136;   // lg[0..21]

    if (lane < 8) pwbuf[128 + lane] = 0.0f;

    const float PI = 3.14159265358979323846f;

    // 7-bit bit-reversal of lane (bit6 = 0 -> r is even)
    const int r = (int)(__brev((unsigned)lane) >> 25);

    // window = sin(pi*n/256) for the 4 loaded samples
    float winv[4];
    #pragma unroll
    for (int j = 0; j < 4; ++j) winv[j] = sinf(PI * (float)(2 * r + j) / 256.0f);

    // twiddles per stage (both lane elements share the same twiddle)
    float twr[6], twi[6];
    #pragma unroll
    for (int s = 0; s < 6; ++s) {
        int m = 1 << s;
        float ang = -PI * (float)(lane & (m - 1)) / (float)m;
        twr[s] = cosf(ang); twi[s] = sinf(ang);
    }
    const float w6r = cosf(-PI * (float)lane / 64.0f);
    const float w6i = sinf(-PI * (float)lane / 64.0f);
    const float c1 = cosf(PI * (float)lane / 128.0f);
    const float s1 = sinf(PI * (float)lane / 128.0f);

    // band weight table (lanes 0..21), support width <= 24, zero padded
    float wtab[24];
    int bstart = 0;
    {
        const int c = lane;
        if (c < NB) {
            const int s_ = (c == 0) ? 0 : c_bands[c - 1];
            bstart = s_;
            const int m = (c > 0 && c < NB - 1) ? c_bands[c] : 0;
            const int e = (c > 0 && c < NB - 1) ? c_bands[c + 1] : 0;
            #pragma unroll
            for (int j = 0; j < 24; ++j) {
                const int k = s_ + j;
                float w = 0.0f;
                if (c == 0) {
                    if (k < 4) w = 2.0f * (1.0f - (float)k * 0.25f);
                } else if (c == NB - 1) {
                    if (k >= 112 && k < 128) w = 2.0f * (float)(k - 112) * (1.0f / 16.0f);
                } else {
                    if (k < m)      w = (float)(k - s_) / (float)(m - s_);
                    else if (k < e) w = 1.0f - (float)(k - m) / (float)(e - m);
                }
                wtab[j] = w;
            }
        } else {
            #pragma unroll
            for (int j = 0; j < 24; ++j) wtab[j] = 0.0f;
        }
    }

    // DCT-II coefficients: lane c computes feat[c] = sum_b coef[b]*lg[b]
    float coef[NB];
    {
        const int c = lane;
        const float norm = sqrtf(2.0f / (float)NB) * ((c == 0) ? (1.0f / sqrtf(2.0f)) : 1.0f);
        #pragma unroll
        for (int b = 0; b < NB; ++b)
            coef[b] = norm * cosf(PI / (float)NB * ((float)b + 0.5f) * (float)c);
    }

    // contiguous frame chunk per wave (adjacent frames share half their input)
    const int chunk = (NFTOT + nwaves - 1) / nwaves;
    int f0 = gwave * chunk;
    int f1 = f0 + chunk; if (f1 > NFTOT) f1 = NFTOT;

    for (int f = f0; f < f1; ++f) {
        const int bb = f / NFR_B;
        const int t  = f - bb * NFR_B;
        const float* xp = x + (size_t)bb * ROWLEN + (size_t)t * 128;

        const float4 v = *(const float4*)(xp + 2 * r);
        float ar = v.x * winv[0], ai = v.y * winv[1];
        float br = v.z * winv[2], bi = v.w * winv[3];

        // 6 cross-lane DIT stages (spans 1..32)
        #pragma unroll
        for (int s = 0; s < 6; ++s) {
            const int m = 1 << s;
            const bool up = (lane & m) != 0;
            const float qar = __shfl_xor(ar, m, 64), qai = __shfl_xor(ai, m, 64);
            const float qbr = __shfl_xor(br, m, 64), qbi = __shfl_xor(bi, m, 64);
            const float wr = twr[s], wi = twi[s];
            {
                const float vr = up ? ar : qar, vi = up ? ai : qai;
                const float ur = up ? qar : ar, ui = up ? qai : ai;
                const float tr = wr * vr - wi * vi, ti = wr * vi + wi * vr;
                ar = up ? ur - tr : ur + tr;
                ai = up ? ui - ti : ui + ti;
            }
            {
                const float vr = up ? br : qbr, vi = up ? bi : qbi;
                const float ur = up ? qbr : br, ui = up ? qbi : bi;
                const float tr = wr * vr - wi * vi, ti = wr * vi + wi * vr;
                br = up ? ur - tr : ur + tr;
                bi = up ? ui - ti : ui + ti;
            }
        }
        // span-64 stage (lane-local)
        {
            const float tr = w6r * br - w6i * bi, ti = w6r * bi + w6i * br;
            const float nar = ar + tr, nai = ai + ti;
            br = ar - tr; bi = ai - ti;
            ar = nar; ai = nai;
        }
        // a = Z[lane], b = Z[lane+64]; Hermitian unpack -> pw[lane], pw[lane+64]
        const int pidx = (64 - lane) & 63;
        const float par = __shfl(ar, pidx, 64), pai = __shfl(ai, pidx, 64);
        const float pbr = __shfl(br, pidx, 64), pbi = __shfl(bi, pidx, 64);
        const float P1r = (lane == 0) ? par : pbr, P1i = (lane == 0) ? pai : pbi;
        const float P2r = (lane == 0) ? pbr : par, P2i = (lane == 0) ? pbi : pai;

        float Er = 0.5f * (ar + P1r), Ei = 0.5f * (ai - P1i);
        float Or_ = 0.5f * (ar - P1r), Oi = 0.5f * (ai + P1i);
        const float X1r = Er + c1 * Oi - s1 * Or_;
        const float X1i = Ei - c1 * Or_ - s1 * Oi;
        const float pw1 = X1r * X1r + X1i * X1i;

        Er = 0.5f * (br + P2r); Ei = 0.5f * (bi - P2i);
        Or_ = 0.5f * (br - P2r); Oi = 0.5f * (bi + P2i);
        const float X2r = Er - s1 * Oi - c1 * Or_;
        const float X2i = Ei + s1 * Or_ - c1 * Oi;
        const float pw2 = X2r * X2r + X2i * X2i;

        pwbuf[lane]      = pw1;
        pwbuf[lane + 64] = pw2;
        asm volatile("s_waitcnt lgkmcnt(0)" ::: "memory");

        if (lane < NB) {
            float bp = 0.0f;
            #pragma unroll
            for (int j = 0; j < 24; ++j) bp += wtab[j] * pwbuf[bstart + j];
            lgbuf[lane] = __log2f(bp) * 0.30102999566398120f;
        }
        asm volatile("s_waitcnt lgkmcnt(0)" ::: "memory");

        if (lane < NB) {
            float acc = 0.0f;
            #pragma unroll
            for (int b = 0; b < NB; ++b) acc += coef[b] * lgbuf[b];
            out[(size_t)f * NB + lane] = acc;
        }
    }
}

extern "C" void kernel_launch(void* const* d_in, const int* in_sizes, int n_in,
                              void* d_out, int out_size, void* d_ws, size_t ws_size,
                              hipStream_t stream) {
    const float* x = (const float*)d_in[0];
    float* out = (float*)d_out;
    feat_kernel<<<2048, 256, 0, stream>>>(x, out);
}